// Round 5
// baseline (155.604 us; speedup 1.0000x reference)
//
#include <hip/hip_runtime.h>

// NCC2D fused single-kernel, single-buffer LDS + VGPR-staged pipeline.
// R4 post-mortem: 75 KB double-buffered LDS -> only 1 block/CU resident
// (Occupancy 11%), so nothing hid latency. Fix: single 9-row buffer
// (18 x 520 x 4 B = 37.4 KB -> 3-4 blocks/CU) and restore overlap by
// staging round R+1 in VGPRs (9 independent float4 loads/thread issued
// before computing round R from LDS). Rounds of NINE keep the vertical
// ring statically indexed (R3 lesson: dynamic ring index -> scratch).
//
// Per round: [issue loads R+1] [compute 9 rows from LDS] barrier
//            [ds_write staged R+1] barrier.
// Thread t: stages quarter-row float4 of array (t>>7) at col 4*(t&127);
// computes cc for columns 2t, 2t+1 (stride-8B LDS reads; known 4-way
// bank conflict ~2.7M cyc — next lever if LDS pipe binds).
// Finish: block reduce -> device atomicAdd + completion counter in d_ws
// (zeroed by hipMemsetAsync); last block writes -mean.

#define BATCH   32
#define IMH     512
#define IMW     512
#define SH      28          // output rows per block
#define NSTRIP  19          // 19*28 = 532 >= 512 (tail masked)
#define NROUND  4           // 36 input rows = 4 rounds x 9
#define NBLOCKS (BATCH * NSTRIP)
#define LROW    520         // [0..4)=0, [4..516)=data, [516..520)=0
#define AROWS   18          // 2 arr x 9 rows (single buffer)
#define LDSZ    (AROWS * LROW)

__global__ __launch_bounds__(256, 3) void ncc_main(const float* __restrict__ I,
                                                   const float* __restrict__ J,
                                                   float* __restrict__ acc_ws,
                                                   unsigned* __restrict__ cnt_ws,
                                                   float* __restrict__ out) {
    __shared__ __align__(16) float lds[LDSZ];
    __shared__ float wsum[4];

    const int t   = threadIdx.x;
    const int s   = blockIdx.x;  // strip
    const int b   = blockIdx.y;  // image
    const int r0  = s * SH;
    const float inv81 = 1.0f / 81.0f;

    const float* Ib = I + (size_t)b * IMH * IMW;
    const float* Jb = J + (size_t)b * IMH * IMW;

    // staging role: arr = t>>7 (0:I rows, 1:J rows), quarter-row col
    const int arr  = t >> 7;
    const int col  = 4 * (t & 127);
    const float* src = arr ? Jb : Ib;
    float* const dstbase = &lds[arr * 9 * LROW + 4 + col];

    float4 stg[9];
    const float4 zero4 = make_float4(0.f, 0.f, 0.f, 0.f);

    auto load_round = [&](int R) {       // 9 independent global float4 loads
#pragma unroll
        for (int q = 0; q < 9; ++q) {
            const int ri = r0 - 4 + R * 9 + q;
            stg[q] = ((unsigned)ri < (unsigned)IMH)
                         ? *(const float4*)(src + (size_t)ri * IMW + col)
                         : zero4;
        }
    };
    auto write_round = [&]() {           // staged VGPRs -> LDS (b128)
#pragma unroll
        for (int q = 0; q < 9; ++q)
            *(float4*)(dstbase + q * LROW) = stg[q];
    };

    // zero the +-4 pads of all 18 LDS rows (once; writes never touch pads)
    if (t < AROWS * 8) {
        const int arow = t >> 3;
        const int k    = t & 7;
        lds[arow * LROW + ((k < 4) ? k : (512 + k))] = 0.f;
    }

    load_round(0);
    write_round();       // compiler waits vmcnt per-use
    __syncthreads();

    // ring[j][q]: horizontal sums H of the last 9 input rows
    // q: 0=I 1=J 2=II 3=JJ 4=IJ ; .x = col 2t, .y = col 2t+1
    float2 ring[9][5];
#pragma unroll
    for (int j = 0; j < 9; ++j)
#pragma unroll
        for (int q = 0; q < 5; ++q) ring[j][q] = make_float2(0.f, 0.f);

    float2 V[5];
#pragma unroll
    for (int q = 0; q < 5; ++q) V[q] = make_float2(0.f, 0.f);

    float2 acc = make_float2(0.f, 0.f);

#pragma unroll 1
    for (int R = 0; R < NROUND; ++R) {
        if (R + 1 < NROUND) load_round(R + 1);   // overlap with compute below

        const int baseI = 2 * t;                  // pads make this col 2t-4
        const int baseJ = 9 * LROW + 2 * t;

#pragma unroll
        for (int j = 0; j < 9; ++j) {      // j IS the ring slot (static)
            const int i = R * 9 + j;       // row iteration 0..35

            float vI[10], vJ[10];
#pragma unroll
            for (int k = 0; k < 5; ++k) {
                const float2 a = *(const float2*)&lds[baseI + j * LROW + 2 * k];
                const float2 c = *(const float2*)&lds[baseJ + j * LROW + 2 * k];
                vI[2 * k] = a.x; vI[2 * k + 1] = a.y;
                vJ[2 * k] = c.x; vJ[2 * k + 1] = c.y;
            }

            float sI = 0.f, sJ = 0.f, sII = 0.f, sJJ = 0.f, sIJ = 0.f;
#pragma unroll
            for (int m = 0; m < 9; ++m) {
                sI  += vI[m];
                sJ  += vJ[m];
                sII += vI[m] * vI[m];
                sJJ += vJ[m] * vJ[m];
                sIJ += vI[m] * vJ[m];
            }
            const float i0 = vI[0], j0 = vJ[0], i9 = vI[9], j9 = vJ[9];
            float2 Hn[5];
            Hn[0] = make_float2(sI,  sI  + i9      - i0);
            Hn[1] = make_float2(sJ,  sJ  + j9      - j0);
            Hn[2] = make_float2(sII, sII + i9 * i9 - i0 * i0);
            Hn[3] = make_float2(sJJ, sJJ + j9 * j9 - j0 * j0);
            Hn[4] = make_float2(sIJ, sIJ + i9 * j9 - i0 * j0);

#pragma unroll
            for (int q = 0; q < 5; ++q) {
                const float2 old = ring[j][q];
                ring[j][q] = Hn[q];
                V[q].x += Hn[q].x - old.x;
                V[q].y += Hn[q].y - old.y;
            }

            if (i >= 8 && (r0 + i - 8) < IMH) {
                {
                    const float aI = V[0].x, aJ = V[1].x;
                    const float cross = V[4].x - aI * aJ * inv81;
                    const float iv    = V[2].x - aI * aI * inv81;
                    const float jv    = V[3].x - aJ * aJ * inv81;
                    acc.x += cross * cross *
                             __builtin_amdgcn_rcpf(iv * jv + 1e-5f);
                }
                {
                    const float aI = V[0].y, aJ = V[1].y;
                    const float cross = V[4].y - aI * aJ * inv81;
                    const float iv    = V[2].y - aI * aI * inv81;
                    const float jv    = V[3].y - aJ * aJ * inv81;
                    acc.y += cross * cross *
                             __builtin_amdgcn_rcpf(iv * jv + 1e-5f);
                }
            }
        }

        if (R + 1 < NROUND) {
            __syncthreads();   // all reads of round R done
            write_round();     // commit staged round R+1
            __syncthreads();   // writes visible before next compute
        }
    }

    // block reduction: wave shuffle, then LDS across the 4 waves
    float sum = acc.x + acc.y;
#pragma unroll
    for (int off = 32; off > 0; off >>= 1) sum += __shfl_down(sum, off, 64);

    if ((t & 63) == 0) wsum[t >> 6] = sum;
    __syncthreads();
    if (t == 0) {
        const float bsum = wsum[0] + wsum[1] + wsum[2] + wsum[3];
        atomicAdd(acc_ws, bsum);          // device-scope
        __threadfence();
        const unsigned old = atomicAdd(cnt_ws, 1u);
        if (old == (unsigned)(NBLOCKS - 1)) {
            const float total = atomicAdd(acc_ws, 0.0f);  // coherent read
            out[0] = -total / 8388608.0f;                 // -mean over 32*512*512
        }
    }
}

extern "C" void kernel_launch(void* const* d_in, const int* in_sizes, int n_in,
                              void* d_out, int out_size, void* d_ws, size_t ws_size,
                              hipStream_t stream) {
    const float* I = (const float*)d_in[0];  // y_true
    const float* J = (const float*)d_in[1];  // y_pred
    float* acc_ws  = (float*)d_ws;           // ws[0]: running sum
    unsigned* cnt  = (unsigned*)d_ws + 1;    // ws[1]: completion counter
    float* out     = (float*)d_out;

    hipMemsetAsync(d_ws, 0, 2 * sizeof(float), stream);

    dim3 grid(NSTRIP, BATCH);
    ncc_main<<<grid, 256, 0, stream>>>(I, J, acc_ws, cnt, out);
}